// Round 4
// baseline (223.413 us; speedup 1.0000x reference)
//
#include <hip/hip_runtime.h>
#include <hip/hip_bf16.h>
#include <math.h>

#define D_MODEL 512
#define D_LOW   64
#define NBINS   39
#define LOG2E   1.4426950408889634f
#define LN2     0.6931471805599453f

typedef __attribute__((ext_vector_type(8))) short short8;
typedef __attribute__((ext_vector_type(4))) float floatx4;

// ---------------------------------------------------------------------------
// Kernel 0 (prep): fold LN affine + log2e into projection weights, ONCE.
//   w2bf[o][c] = bf16(w[o][c]*ln_w[c]*scale), w2sum[o] = sum_c (bf16-rounded),
//   b2[o] = scale*(b[o] + sum_c w[o][c]*ln_b[c]),  scale = log2e for U half.
// Also zeroes the completion counter used by pair's fused finalize.
// ---------------------------------------------------------------------------
__global__ __launch_bounds__(256) void prep_kernel(
    const float* __restrict__ ln_w, const float* __restrict__ ln_b,
    const float* __restrict__ wu_w, const float* __restrict__ wu_b,
    const float* __restrict__ wv_w, const float* __restrict__ wv_b,
    __hip_bfloat16* __restrict__ w2bf, float* __restrict__ w2sum,
    float* __restrict__ b2, int* __restrict__ ctr) {
  __shared__ float red[8];
  const int tid = threadIdx.x;
  const int o = blockIdx.x;
  if (o == 0 && tid == 0) *ctr = 0;
  const bool isU = (o < 64);
  const float* wrow = isU ? (wu_w + o * D_MODEL) : (wv_w + (o - 64) * D_MODEL);
  const float scale = isU ? LOG2E : 1.0f;

  float s1 = 0.f, s2 = 0.f;
  #pragma unroll
  for (int cc = 0; cc < 2; ++cc) {
    const int c = tid + cc * 256;
    const float w  = wrow[c];
    const float w2 = w * ln_w[c] * scale;
    const __hip_bfloat16 hb = __float2bfloat16(w2);
    w2bf[o * D_MODEL + c] = hb;
    s1 += __bfloat162float(hb);
    s2 += w * ln_b[c];
  }
  #pragma unroll
  for (int off = 32; off; off >>= 1) {
    s1 += __shfl_xor(s1, off);
    s2 += __shfl_xor(s2, off);
  }
  const int wave = tid >> 6, lane = tid & 63;
  if (lane == 0) { red[wave] = s1; red[4 + wave] = s2; }
  __syncthreads();
  if (tid == 0) {
    w2sum[o] = red[0] + red[1] + red[2] + red[3];
    const float ss2 = red[4] + red[5] + red[6] + red[7];
    b2[o] = scale * ((isU ? wu_b[o] : wv_b[o - 64]) + ss2);
  }
}

// ---------------------------------------------------------------------------
// Kernel 1 (lnproj): one wave per block, grid = (BN/16) * 8. (r2 version)
// ---------------------------------------------------------------------------
__global__ __launch_bounds__(64) void lnproj_kernel(
    const float* __restrict__ h_res, const __hip_bfloat16* __restrict__ w2bf,
    const float* __restrict__ w2sum, const float* __restrict__ b2,
    float* __restrict__ U, __hip_bfloat16* __restrict__ Vbf, int N) {
  const int lane = threadIdx.x;
  const int q = lane >> 4, ln16 = lane & 15;
  const int rt = blockIdx.x >> 3, og = blockIdx.x & 7;
  const int row0 = rt * 16;
  const float* hp = h_res + (size_t)(row0 + ln16) * D_MODEL + q * 8;

  short8 abf[16];
  float sum = 0.f, ssq = 0.f;
  #pragma unroll
  for (int kc = 0; kc < 16; ++kc) {
    const floatx4 x0 = *reinterpret_cast<const floatx4*>(hp + kc * 32);
    const floatx4 x1 = *reinterpret_cast<const floatx4*>(hp + kc * 32 + 4);
    short8 a;
    #pragma unroll
    for (int e = 0; e < 4; ++e) {
      sum += x0[e]; ssq += x0[e] * x0[e];
      const __hip_bfloat16 hb = __float2bfloat16(x0[e]);
      a[e] = *reinterpret_cast<const short*>(&hb);
    }
    #pragma unroll
    for (int e = 0; e < 4; ++e) {
      sum += x1[e]; ssq += x1[e] * x1[e];
      const __hip_bfloat16 hb = __float2bfloat16(x1[e]);
      a[4 + e] = *reinterpret_cast<const short*>(&hb);
    }
    abf[kc] = a;
  }
  sum += __shfl_xor(sum, 16); sum += __shfl_xor(sum, 32);
  ssq += __shfl_xor(ssq, 16); ssq += __shfl_xor(ssq, 32);
  const float mu  = sum * (1.0f / (float)D_MODEL);
  const float var = ssq * (1.0f / (float)D_MODEL) - mu * mu;
  const float rs  = rsqrtf(var + 1e-5f);
  float mu_r[4], rs_r[4];
  #pragma unroll
  for (int r = 0; r < 4; ++r) {
    mu_r[r] = __shfl(mu, q * 4 + r);
    rs_r[r] = __shfl(rs, q * 4 + r);
  }

  const int out = og * 16 + ln16;            // 0..127
  const short* wp = reinterpret_cast<const short*>(w2bf);
  floatx4 acc = (floatx4){0.f, 0.f, 0.f, 0.f};
  #pragma unroll
  for (int kc = 0; kc < 16; ++kc) {
    const short8 bfr = *reinterpret_cast<const short8*>(
        wp + (size_t)out * D_MODEL + kc * 32 + q * 8);
    acc = __builtin_amdgcn_mfma_f32_16x16x32_bf16(abf[kc], bfr, acc, 0, 0, 0);
  }

  const float ws = w2sum[out];
  const float bb = b2[out];
  #pragma unroll
  for (int r = 0; r < 4; ++r) {
    const int rowg = row0 + q * 4 + r;
    const float val = rs_r[r] * acc[r] - mu_r[r] * rs_r[r] * ws + bb;
    if (out < 64) {
      U[(size_t)rowg * D_LOW + out] = val;
    } else {
      Vbf[(size_t)rowg * D_LOW + (out - 64)] = __float2bfloat16(val);
    }
  }
}

// ---------------------------------------------------------------------------
// Kernel 1.5 (wprep): build each (b,i)'s 6 MFMA A-operand fragments ONCE
// (round-0 version, verified). wb_w staged to LDS with stride-65 padding.
// 4 rows/block, grid = BN/4. Removes ~200 dependent VALU from every pair
// wave (the r1/r3 inline build was on pair's critical path, 16x redundant).
// ---------------------------------------------------------------------------
__global__ __launch_bounds__(256) void wprep_kernel(
    const float* __restrict__ U, const float* __restrict__ wb_w,
    short* __restrict__ wfragbuf, int BN) {
  __shared__ float wsh[NBINS * 65];
  const int tid = threadIdx.x;
  for (int e = tid; e < NBINS * D_LOW; e += 256) {
    const int n = e >> 6, c = e & 63;
    wsh[n * 65 + c] = wb_w[e];
  }
  __syncthreads();

  const int wave = tid >> 6, lane = tid & 63;
  const int q = lane >> 4, ln16 = lane & 15;
  const int rowi = blockIdx.x * 4 + wave;
  const float* Up = U + (size_t)rowi * D_LOW;

  float u[16];
  #pragma unroll
  for (int s = 0; s < 2; ++s)
    #pragma unroll
    for (int e = 0; e < 8; ++e) u[s * 8 + e] = Up[s * 32 + q * 8 + e];

  short* outp = wfragbuf + (size_t)rowi * 6 * 64 * 8;
  #pragma unroll
  for (int t = 0; t < 3; ++t) {
    const int n = t * 16 + ln16;
    #pragma unroll
    for (int s = 0; s < 2; ++s) {
      short8 f;
      #pragma unroll
      for (int e = 0; e < 8; ++e) {
        const float w = (n < NBINS) ? wsh[n * 65 + s * 32 + q * 8 + e] : 0.f;
        const float v = u[s * 8 + e] * w;
        const __hip_bfloat16 hb = __float2bfloat16(v);
        f[e] = *reinterpret_cast<const short*>(&hb);
      }
      *reinterpret_cast<short8*>(outp + ((size_t)(t * 2 + s) * 64 + lane) * 8) = f;
    }
  }
}

// ---------------------------------------------------------------------------
// Kernel 2 (pair): grid (N, 4B) x 256. IT=1, each wave = 1 i x 48 j (3 tiles,
// quarter qtr = blockIdx.y & 3). All memory (6 wfrag, 3 V tiles, tbin coords)
// issued up-front; low VGPR (~100) for 4-5 waves/SIMD; 24.6k waves total.
// Finalize fused via last-block ticket (r3 pattern, verified).
// ---------------------------------------------------------------------------
__global__ __launch_bounds__(256) void pair_kernel(
    const short* __restrict__ wfragbuf,          // [BN][6][64][8] shorts
    const __hip_bfloat16* __restrict__ Vbf,      // [BN][64] bf16
    const float* __restrict__ wb_b,
    const float* __restrict__ x_true, const float* __restrict__ pmask,
    float* __restrict__ part, int* __restrict__ ctr,
    float* __restrict__ out, int N) {
  __shared__ float rbuf[8];
  __shared__ int is_last;
  const int i    = blockIdx.x;
  const int b    = blockIdx.y >> 2;
  const int qtr  = blockIdx.y & 3;
  const int tid  = threadIdx.x;
  const int wave = tid >> 6, lane = tid & 63;
  const int q = lane >> 4, ln16 = lane & 15;
  const int rowi = b * N + i;
  const int jbase = qtr * (N >> 2) + wave * (N >> 4);   // 48-j chunk per wave
  const int q4 = q * 4;

  // ---- wfrag loads (precomputed, coalesced 16B/lane) ----
  short8 wfrag[3][2];
  {
    const short* wfp = wfragbuf + (size_t)rowi * 6 * 64 * 8;
    #pragma unroll
    for (int t = 0; t < 3; ++t)
      #pragma unroll
      for (int s = 0; s < 2; ++s)
        wfrag[t][s] = *reinterpret_cast<const short8*>(
            wfp + ((size_t)(t * 2 + s) * 64 + lane) * 8);
  }

  // ---- V tiles up-front ----
  const short* Vp = reinterpret_cast<const short*>(Vbf) + (size_t)b * N * D_LOW;
  short8 v[3][2];
  #pragma unroll
  for (int tl = 0; tl < 3; ++tl) {
    const size_t jr = jbase + tl * 16 + ln16;
    v[tl][0] = *reinterpret_cast<const short8*>(Vp + jr * D_LOW + q * 8);
    v[tl][1] = *reinterpret_cast<const short8*>(Vp + jr * D_LOW + 32 + q * 8);
  }

  // ---- tbin: 3 tiles ----
  const float xi0 = x_true[rowi * 3 + 0];
  const float xi1 = x_true[rowi * 3 + 1];
  const float xi2 = x_true[rowi * 3 + 2];
  const float pmi = pmask[rowi];
  const float BW  = (22.0f - 2.0f) / 38.0f;
  int tbv[3];
  #pragma unroll
  for (int tl = 0; tl < 3; ++tl) {
    const int rowj = b * N + jbase + tl * 16 + ln16;
    const float dx = xi0 - x_true[rowj * 3 + 0];
    const float dy = xi1 - x_true[rowj * 3 + 1];
    const float dz = xi2 - x_true[rowj * 3 + 2];
    const float d  = sqrtf(dx * dx + dy * dy + dz * dz);
    int tb = (int)((d - 2.0f) / BW);
    tb = tb < 0 ? 0 : (tb > NBINS - 1 ? NBINS - 1 : tb);
    tbv[tl] = (pmi * pmask[rowj] > 0.f) ? tb : -1;
  }

  floatx4 bias_init[3];
  #pragma unroll
  for (int t = 0; t < 3; ++t)
    #pragma unroll
    for (int r = 0; r < 4; ++r) {
      const int bin = t * 16 + q * 4 + r;
      bias_init[t][r] = (bin < NBINS) ? LOG2E * wb_b[bin] : -INFINITY;
    }

  float ce_sum = 0.f, cnt_sum = 0.f;
  #pragma unroll
  for (int tl = 0; tl < 3; ++tl) {
    floatx4 f[3];
    #pragma unroll
    for (int t = 0; t < 3; ++t) {
      floatx4 a = bias_init[t];
      a = __builtin_amdgcn_mfma_f32_16x16x32_bf16(wfrag[t][0], v[tl][0], a, 0, 0, 0);
      a = __builtin_amdgcn_mfma_f32_16x16x32_bf16(wfrag[t][1], v[tl][1], a, 0, 0, 0);
      f[t] = a;
    }

    const int tb  = tbv[tl];
    const int tbq = tb - q4;
    float s0 = 0.f, s1 = 0.f, s2 = 0.f, s3 = 0.f, lt = 0.f;
    #pragma unroll
    for (int t = 0; t < 3; ++t) {
      const floatx4 fv = f[t];
      s0 += __builtin_amdgcn_exp2f(fv[0]);
      s1 += __builtin_amdgcn_exp2f(fv[1]);
      s2 += __builtin_amdgcn_exp2f(fv[2]);
      s3 += __builtin_amdgcn_exp2f(fv[3]);
      lt += (tbq == t * 16 + 0) ? fv[0] : 0.f;
      lt += (tbq == t * 16 + 1) ? fv[1] : 0.f;
      lt += (tbq == t * 16 + 2) ? fv[2] : 0.f;
      lt += (tbq == t * 16 + 3) ? fv[3] : 0.f;
    }
    float ssum = (s0 + s1) + (s2 + s3);
    ssum += __shfl_xor(ssum, 16); ssum += __shfl_xor(ssum, 32);
    const float ok = (tb >= 0) ? 1.f : 0.f;
    ce_sum  += ok * LN2 * (__builtin_amdgcn_logf(ssum) - 4.0f * lt);
    cnt_sum += ok;
  }

  #pragma unroll
  for (int off = 32; off; off >>= 1) {
    ce_sum  += __shfl_xor(ce_sum, off);
    cnt_sum += __shfl_xor(cnt_sum, off);
  }
  if (lane == 0) { rbuf[wave] = ce_sum; rbuf[4 + wave] = cnt_sum; }
  __syncthreads();

  const int nblocks = N * 8;   // gridDim = (N, 4B), B = 2
  if (tid == 0) {
    const size_t slot = ((size_t)blockIdx.y * N + blockIdx.x) * 2;
    part[slot + 0] = rbuf[0] + rbuf[1] + rbuf[2] + rbuf[3];
    part[slot + 1] = rbuf[4] + rbuf[5] + rbuf[6] + rbuf[7];
    __threadfence();
    const int t = atomicAdd(ctr, 1);
    is_last = (t == nblocks - 1) ? 1 : 0;
  }
  __syncthreads();

  if (is_last) {
    // ---- fused finalize (identical reduction order to the old kernel) ----
    __threadfence();
    __shared__ float red[8];
    float loss = 0.f, vcount = 0.f;
    const int nper = 4 * N;    // slots per batch sample (4 j-quarters x N i)
    for (int bb = 0; bb < 2; ++bb) {
      float ce = 0.f, cnt = 0.f;
      for (int e = tid; e < nper; e += 256) {
        const size_t base = ((size_t)bb * nper + e) * 2;
        ce  += part[base + 0];
        cnt += part[base + 1];
      }
      #pragma unroll
      for (int off = 32; off; off >>= 1) {
        ce  += __shfl_xor(ce, off);
        cnt += __shfl_xor(cnt, off);
      }
      if (lane == 0) { red[wave] = ce; red[4 + wave] = cnt; }
      __syncthreads();
      if (tid == 0) {
        const float s = red[0] + red[1] + red[2] + red[3];
        const float c = red[4] + red[5] + red[6] + red[7];
        if (c > 0.f) { loss += s / fmaxf(c, 1.f); vcount += 1.f; }
      }
      __syncthreads();
    }
    if (tid == 0) out[0] = (vcount > 0.f) ? loss / vcount : 0.f;
  }
}

extern "C" void kernel_launch(void* const* d_in, const int* in_sizes, int n_in,
                              void* d_out, int out_size, void* d_ws, size_t ws_size,
                              hipStream_t stream) {
  const float* h_res  = (const float*)d_in[0];
  const float* x_true = (const float*)d_in[1];
  const float* pmask  = (const float*)d_in[2];
  const float* ln_w   = (const float*)d_in[3];
  const float* ln_b   = (const float*)d_in[4];
  const float* wu_w   = (const float*)d_in[5];
  const float* wu_b   = (const float*)d_in[6];
  const float* wv_w   = (const float*)d_in[7];
  const float* wv_b   = (const float*)d_in[8];
  const float* wb_w   = (const float*)d_in[9];
  const float* wb_b   = (const float*)d_in[10];

  const int B  = 2;
  const int N  = in_sizes[2] / B;
  const int BN = B * N;

  // ws: U f32[BN*64] | Vbf bf16[BN*64] | part f32[8N*2] | ctr int[64]
  //     | w2bf bf16[128*512] | w2sum f32[128] | b2 f32[128]
  //     | wfragbuf short[BN*6*64*8]
  float* U = (float*)d_ws;
  __hip_bfloat16* Vbf = (__hip_bfloat16*)(U + (size_t)BN * D_LOW);
  float* part = (float*)(Vbf + (size_t)BN * D_LOW);
  int* ctr = (int*)(part + (size_t)8 * N * 2);
  __hip_bfloat16* w2bf = (__hip_bfloat16*)(ctr + 64);
  float* w2sum = (float*)(w2bf + 128 * D_MODEL);
  float* b2    = w2sum + 128;
  short* wfragbuf = (short*)(b2 + 128);

  prep_kernel<<<128, 256, 0, stream>>>(ln_w, ln_b, wu_w, wu_b, wv_w, wv_b,
                                       w2bf, w2sum, b2, ctr);
  lnproj_kernel<<<(BN / 16) * 8, 64, 0, stream>>>(h_res, w2bf, w2sum, b2,
                                                  U, Vbf, N);
  wprep_kernel<<<BN / 4, 256, 0, stream>>>(U, wb_w, wfragbuf, BN);
  pair_kernel<<<dim3(N, 4 * B), 256, 0, stream>>>(
      wfragbuf, Vbf, wb_b, x_true, pmask, part, ctr, (float*)d_out, N);
}

// Round 5
// 132.018 us; speedup vs baseline: 1.6923x; 1.6923x over previous
//
#include <hip/hip_runtime.h>
#include <hip/hip_bf16.h>
#include <math.h>

#define D_MODEL 512
#define D_LOW   64
#define NBINS   39
#define LOG2E   1.4426950408889634f
#define LN2     0.6931471805599453f

typedef __attribute__((ext_vector_type(8))) short short8;
typedef __attribute__((ext_vector_type(4))) float floatx4;

// ---------------------------------------------------------------------------
// Kernel 0 (prep): fold LN affine + log2e into projection weights, ONCE.
//   w2bf[o][c] = bf16(w[o][c]*ln_w[c]*scale), w2sum[o] = sum_c (bf16-rounded),
//   b2[o] = scale*(b[o] + sum_c w[o][c]*ln_b[c]),  scale = log2e for U half.
// ---------------------------------------------------------------------------
__global__ __launch_bounds__(256) void prep_kernel(
    const float* __restrict__ ln_w, const float* __restrict__ ln_b,
    const float* __restrict__ wu_w, const float* __restrict__ wu_b,
    const float* __restrict__ wv_w, const float* __restrict__ wv_b,
    __hip_bfloat16* __restrict__ w2bf, float* __restrict__ w2sum,
    float* __restrict__ b2) {
  __shared__ float red[8];
  const int tid = threadIdx.x;
  const int o = blockIdx.x;
  const bool isU = (o < 64);
  const float* wrow = isU ? (wu_w + o * D_MODEL) : (wv_w + (o - 64) * D_MODEL);
  const float scale = isU ? LOG2E : 1.0f;

  float s1 = 0.f, s2 = 0.f;
  #pragma unroll
  for (int cc = 0; cc < 2; ++cc) {
    const int c = tid + cc * 256;
    const float w  = wrow[c];
    const float w2 = w * ln_w[c] * scale;
    const __hip_bfloat16 hb = __float2bfloat16(w2);
    w2bf[o * D_MODEL + c] = hb;
    s1 += __bfloat162float(hb);
    s2 += w * ln_b[c];
  }
  #pragma unroll
  for (int off = 32; off; off >>= 1) {
    s1 += __shfl_xor(s1, off);
    s2 += __shfl_xor(s2, off);
  }
  const int wave = tid >> 6, lane = tid & 63;
  if (lane == 0) { red[wave] = s1; red[4 + wave] = s2; }
  __syncthreads();
  if (tid == 0) {
    w2sum[o] = red[0] + red[1] + red[2] + red[3];
    const float ss2 = red[4] + red[5] + red[6] + red[7];
    b2[o] = scale * ((isU ? wu_b[o] : wv_b[o - 64]) + ss2);
  }
}

// ---------------------------------------------------------------------------
// Kernel 1 (lnproj): one wave per block, grid = (BN/16) * 8. (r2 version)
// ---------------------------------------------------------------------------
__global__ __launch_bounds__(64) void lnproj_kernel(
    const float* __restrict__ h_res, const __hip_bfloat16* __restrict__ w2bf,
    const float* __restrict__ w2sum, const float* __restrict__ b2,
    float* __restrict__ U, __hip_bfloat16* __restrict__ Vbf, int N) {
  const int lane = threadIdx.x;
  const int q = lane >> 4, ln16 = lane & 15;
  const int rt = blockIdx.x >> 3, og = blockIdx.x & 7;
  const int row0 = rt * 16;
  const float* hp = h_res + (size_t)(row0 + ln16) * D_MODEL + q * 8;

  short8 abf[16];
  float sum = 0.f, ssq = 0.f;
  #pragma unroll
  for (int kc = 0; kc < 16; ++kc) {
    const floatx4 x0 = *reinterpret_cast<const floatx4*>(hp + kc * 32);
    const floatx4 x1 = *reinterpret_cast<const floatx4*>(hp + kc * 32 + 4);
    short8 a;
    #pragma unroll
    for (int e = 0; e < 4; ++e) {
      sum += x0[e]; ssq += x0[e] * x0[e];
      const __hip_bfloat16 hb = __float2bfloat16(x0[e]);
      a[e] = *reinterpret_cast<const short*>(&hb);
    }
    #pragma unroll
    for (int e = 0; e < 4; ++e) {
      sum += x1[e]; ssq += x1[e] * x1[e];
      const __hip_bfloat16 hb = __float2bfloat16(x1[e]);
      a[4 + e] = *reinterpret_cast<const short*>(&hb);
    }
    abf[kc] = a;
  }
  sum += __shfl_xor(sum, 16); sum += __shfl_xor(sum, 32);
  ssq += __shfl_xor(ssq, 16); ssq += __shfl_xor(ssq, 32);
  const float mu  = sum * (1.0f / (float)D_MODEL);
  const float var = ssq * (1.0f / (float)D_MODEL) - mu * mu;
  const float rs  = rsqrtf(var + 1e-5f);
  float mu_r[4], rs_r[4];
  #pragma unroll
  for (int r = 0; r < 4; ++r) {
    mu_r[r] = __shfl(mu, q * 4 + r);
    rs_r[r] = __shfl(rs, q * 4 + r);
  }

  const int out = og * 16 + ln16;            // 0..127
  const short* wp = reinterpret_cast<const short*>(w2bf);
  floatx4 acc = (floatx4){0.f, 0.f, 0.f, 0.f};
  #pragma unroll
  for (int kc = 0; kc < 16; ++kc) {
    const short8 bfr = *reinterpret_cast<const short8*>(
        wp + (size_t)out * D_MODEL + kc * 32 + q * 8);
    acc = __builtin_amdgcn_mfma_f32_16x16x32_bf16(abf[kc], bfr, acc, 0, 0, 0);
  }

  const float ws = w2sum[out];
  const float bb = b2[out];
  #pragma unroll
  for (int r = 0; r < 4; ++r) {
    const int rowg = row0 + q * 4 + r;
    const float val = rs_r[r] * acc[r] - mu_r[r] * rs_r[r] * ws + bb;
    if (out < 64) {
      U[(size_t)rowg * D_LOW + out] = val;
    } else {
      Vbf[(size_t)rowg * D_LOW + (out - 64)] = __float2bfloat16(val);
    }
  }
}

// ---------------------------------------------------------------------------
// Kernel 1.5 (wprep): build each (b,i)'s 6 MFMA A-operand fragments ONCE.
// wb_w staged to LDS with stride-65 padding. 4 rows/block, grid = BN/4.
// ---------------------------------------------------------------------------
__global__ __launch_bounds__(256) void wprep_kernel(
    const float* __restrict__ U, const float* __restrict__ wb_w,
    short* __restrict__ wfragbuf, int BN) {
  __shared__ float wsh[NBINS * 65];
  const int tid = threadIdx.x;
  for (int e = tid; e < NBINS * D_LOW; e += 256) {
    const int n = e >> 6, c = e & 63;
    wsh[n * 65 + c] = wb_w[e];
  }
  __syncthreads();

  const int wave = tid >> 6, lane = tid & 63;
  const int q = lane >> 4, ln16 = lane & 15;
  const int rowi = blockIdx.x * 4 + wave;
  const float* Up = U + (size_t)rowi * D_LOW;

  float u[16];
  #pragma unroll
  for (int s = 0; s < 2; ++s)
    #pragma unroll
    for (int e = 0; e < 8; ++e) u[s * 8 + e] = Up[s * 32 + q * 8 + e];

  short* outp = wfragbuf + (size_t)rowi * 6 * 64 * 8;
  #pragma unroll
  for (int t = 0; t < 3; ++t) {
    const int n = t * 16 + ln16;
    #pragma unroll
    for (int s = 0; s < 2; ++s) {
      short8 f;
      #pragma unroll
      for (int e = 0; e < 8; ++e) {
        const float w = (n < NBINS) ? wsh[n * 65 + s * 32 + q * 8 + e] : 0.f;
        const float v = u[s * 8 + e] * w;
        const __hip_bfloat16 hb = __float2bfloat16(v);
        f[e] = *reinterpret_cast<const short*>(&hb);
      }
      *reinterpret_cast<short8*>(outp + ((size_t)(t * 2 + s) * 64 + lane) * 8) = f;
    }
  }
}

// ---------------------------------------------------------------------------
// Kernel 2 (pair): grid (N, 4B) x 256. IT=1, each wave = 1 i x 48 j (3 tiles,
// quarter qtr = blockIdx.y & 3). All memory (6 wfrag, 3 V tiles, tbin coords)
// issued up-front; low VGPR (~56) for high occupancy; 24.6k waves total.
// NO last-block ticket: r4 showed per-block __threadfence+atomicAdd serializes
// at ~20 ns/block (6144 blocks ~ 123 us). Finalize is a separate dispatch.
// ---------------------------------------------------------------------------
__global__ __launch_bounds__(256) void pair_kernel(
    const short* __restrict__ wfragbuf,          // [BN][6][64][8] shorts
    const __hip_bfloat16* __restrict__ Vbf,      // [BN][64] bf16
    const float* __restrict__ wb_b,
    const float* __restrict__ x_true, const float* __restrict__ pmask,
    float* __restrict__ part, int N) {
  __shared__ float rbuf[8];
  const int i    = blockIdx.x;
  const int b    = blockIdx.y >> 2;
  const int qtr  = blockIdx.y & 3;
  const int tid  = threadIdx.x;
  const int wave = tid >> 6, lane = tid & 63;
  const int q = lane >> 4, ln16 = lane & 15;
  const int rowi = b * N + i;
  const int jbase = qtr * (N >> 2) + wave * (N >> 4);   // 48-j chunk per wave
  const int q4 = q * 4;

  // ---- wfrag loads (precomputed, coalesced 16B/lane) ----
  short8 wfrag[3][2];
  {
    const short* wfp = wfragbuf + (size_t)rowi * 6 * 64 * 8;
    #pragma unroll
    for (int t = 0; t < 3; ++t)
      #pragma unroll
      for (int s = 0; s < 2; ++s)
        wfrag[t][s] = *reinterpret_cast<const short8*>(
            wfp + ((size_t)(t * 2 + s) * 64 + lane) * 8);
  }

  // ---- V tiles up-front ----
  const short* Vp = reinterpret_cast<const short*>(Vbf) + (size_t)b * N * D_LOW;
  short8 v[3][2];
  #pragma unroll
  for (int tl = 0; tl < 3; ++tl) {
    const size_t jr = jbase + tl * 16 + ln16;
    v[tl][0] = *reinterpret_cast<const short8*>(Vp + jr * D_LOW + q * 8);
    v[tl][1] = *reinterpret_cast<const short8*>(Vp + jr * D_LOW + 32 + q * 8);
  }

  // ---- tbin: 3 tiles ----
  const float xi0 = x_true[rowi * 3 + 0];
  const float xi1 = x_true[rowi * 3 + 1];
  const float xi2 = x_true[rowi * 3 + 2];
  const float pmi = pmask[rowi];
  const float BW  = (22.0f - 2.0f) / 38.0f;
  int tbv[3];
  #pragma unroll
  for (int tl = 0; tl < 3; ++tl) {
    const int rowj = b * N + jbase + tl * 16 + ln16;
    const float dx = xi0 - x_true[rowj * 3 + 0];
    const float dy = xi1 - x_true[rowj * 3 + 1];
    const float dz = xi2 - x_true[rowj * 3 + 2];
    const float d  = sqrtf(dx * dx + dy * dy + dz * dz);
    int tb = (int)((d - 2.0f) / BW);
    tb = tb < 0 ? 0 : (tb > NBINS - 1 ? NBINS - 1 : tb);
    tbv[tl] = (pmi * pmask[rowj] > 0.f) ? tb : -1;
  }

  floatx4 bias_init[3];
  #pragma unroll
  for (int t = 0; t < 3; ++t)
    #pragma unroll
    for (int r = 0; r < 4; ++r) {
      const int bin = t * 16 + q * 4 + r;
      bias_init[t][r] = (bin < NBINS) ? LOG2E * wb_b[bin] : -INFINITY;
    }

  float ce_sum = 0.f, cnt_sum = 0.f;
  #pragma unroll
  for (int tl = 0; tl < 3; ++tl) {
    floatx4 f[3];
    #pragma unroll
    for (int t = 0; t < 3; ++t) {
      floatx4 a = bias_init[t];
      a = __builtin_amdgcn_mfma_f32_16x16x32_bf16(wfrag[t][0], v[tl][0], a, 0, 0, 0);
      a = __builtin_amdgcn_mfma_f32_16x16x32_bf16(wfrag[t][1], v[tl][1], a, 0, 0, 0);
      f[t] = a;
    }

    const int tb  = tbv[tl];
    const int tbq = tb - q4;
    float s0 = 0.f, s1 = 0.f, s2 = 0.f, s3 = 0.f, lt = 0.f;
    #pragma unroll
    for (int t = 0; t < 3; ++t) {
      const floatx4 fv = f[t];
      s0 += __builtin_amdgcn_exp2f(fv[0]);
      s1 += __builtin_amdgcn_exp2f(fv[1]);
      s2 += __builtin_amdgcn_exp2f(fv[2]);
      s3 += __builtin_amdgcn_exp2f(fv[3]);
      lt += (tbq == t * 16 + 0) ? fv[0] : 0.f;
      lt += (tbq == t * 16 + 1) ? fv[1] : 0.f;
      lt += (tbq == t * 16 + 2) ? fv[2] : 0.f;
      lt += (tbq == t * 16 + 3) ? fv[3] : 0.f;
    }
    float ssum = (s0 + s1) + (s2 + s3);
    ssum += __shfl_xor(ssum, 16); ssum += __shfl_xor(ssum, 32);
    const float ok = (tb >= 0) ? 1.f : 0.f;
    ce_sum  += ok * LN2 * (__builtin_amdgcn_logf(ssum) - 4.0f * lt);
    cnt_sum += ok;
  }

  #pragma unroll
  for (int off = 32; off; off >>= 1) {
    ce_sum  += __shfl_xor(ce_sum, off);
    cnt_sum += __shfl_xor(cnt_sum, off);
  }
  if (lane == 0) { rbuf[wave] = ce_sum; rbuf[4 + wave] = cnt_sum; }
  __syncthreads();
  if (tid == 0) {
    const size_t slot = ((size_t)blockIdx.y * N + blockIdx.x) * 2;
    part[slot + 0] = rbuf[0] + rbuf[1] + rbuf[2] + rbuf[3];
    part[slot + 1] = rbuf[4] + rbuf[5] + rbuf[6] + rbuf[7];
  }
}

// ---------------------------------------------------------------------------
// Kernel 3: finalize — batch b owns slots [b*4N, (b+1)*4N) (4 j-quarters x N).
// ---------------------------------------------------------------------------
__global__ __launch_bounds__(256) void finalize_kernel(
    const float* __restrict__ part, float* __restrict__ out, int N, int B) {
  __shared__ float red[8];
  const int tid = threadIdx.x, wave = tid >> 6, lane = tid & 63;
  float loss = 0.f, vcount = 0.f;
  const int nper = 4 * N;
  for (int b = 0; b < B; ++b) {
    float ce = 0.f, cnt = 0.f;
    for (int e = tid; e < nper; e += 256) {
      const size_t base = ((size_t)b * nper + e) * 2;
      ce  += part[base + 0];
      cnt += part[base + 1];
    }
    #pragma unroll
    for (int off = 32; off; off >>= 1) {
      ce  += __shfl_xor(ce, off);
      cnt += __shfl_xor(cnt, off);
    }
    if (lane == 0) { red[wave] = ce; red[4 + wave] = cnt; }
    __syncthreads();
    if (tid == 0) {
      const float s = red[0] + red[1] + red[2] + red[3];
      const float c = red[4] + red[5] + red[6] + red[7];
      if (c > 0.f) { loss += s / fmaxf(c, 1.f); vcount += 1.f; }
    }
    __syncthreads();
  }
  if (tid == 0) out[0] = (vcount > 0.f) ? loss / vcount : 0.f;
}

extern "C" void kernel_launch(void* const* d_in, const int* in_sizes, int n_in,
                              void* d_out, int out_size, void* d_ws, size_t ws_size,
                              hipStream_t stream) {
  const float* h_res  = (const float*)d_in[0];
  const float* x_true = (const float*)d_in[1];
  const float* pmask  = (const float*)d_in[2];
  const float* ln_w   = (const float*)d_in[3];
  const float* ln_b   = (const float*)d_in[4];
  const float* wu_w   = (const float*)d_in[5];
  const float* wu_b   = (const float*)d_in[6];
  const float* wv_w   = (const float*)d_in[7];
  const float* wv_b   = (const float*)d_in[8];
  const float* wb_w   = (const float*)d_in[9];
  const float* wb_b   = (const float*)d_in[10];

  const int B  = 2;
  const int N  = in_sizes[2] / B;
  const int BN = B * N;

  // ws: U f32[BN*64] | Vbf bf16[BN*64] | part f32[8N*2]
  //     | w2bf bf16[128*512] | w2sum f32[128] | b2 f32[128]
  //     | wfragbuf short[BN*6*64*8]
  float* U = (float*)d_ws;
  __hip_bfloat16* Vbf = (__hip_bfloat16*)(U + (size_t)BN * D_LOW);
  float* part = (float*)(Vbf + (size_t)BN * D_LOW);
  __hip_bfloat16* w2bf = (__hip_bfloat16*)(part + (size_t)8 * N * 2);
  float* w2sum = (float*)(w2bf + 128 * D_MODEL);
  float* b2    = w2sum + 128;
  short* wfragbuf = (short*)(b2 + 128);

  prep_kernel<<<128, 256, 0, stream>>>(ln_w, ln_b, wu_w, wu_b, wv_w, wv_b,
                                       w2bf, w2sum, b2);
  lnproj_kernel<<<(BN / 16) * 8, 64, 0, stream>>>(h_res, w2bf, w2sum, b2,
                                                  U, Vbf, N);
  wprep_kernel<<<BN / 4, 256, 0, stream>>>(U, wb_w, wfragbuf, BN);
  pair_kernel<<<dim3(N, 4 * B), 256, 0, stream>>>(
      wfragbuf, Vbf, wb_b, x_true, pmask, part, N);
  finalize_kernel<<<1, 256, 0, stream>>>(part, (float*)d_out, N, B);
}

// Round 6
// 124.522 us; speedup vs baseline: 1.7942x; 1.0602x over previous
//
#include <hip/hip_runtime.h>
#include <hip/hip_bf16.h>
#include <math.h>

#define D_MODEL 512
#define D_LOW   64
#define NBINS   39
#define LOG2E   1.4426950408889634f
#define LN2     0.6931471805599453f

typedef __attribute__((ext_vector_type(8))) short short8;
typedef __attribute__((ext_vector_type(4))) float floatx4;

// ---------------------------------------------------------------------------
// Kernel 0 (prep): fold LN affine + log2e into projection weights, ONCE.
//   w2bf[o][c] = bf16(w[o][c]*ln_w[c]*scale), w2sum[o] = sum_c (bf16-rounded),
//   b2[o] = scale*(b[o] + sum_c w[o][c]*ln_b[c]),  scale = log2e for U half.
// ---------------------------------------------------------------------------
__global__ __launch_bounds__(256) void prep_kernel(
    const float* __restrict__ ln_w, const float* __restrict__ ln_b,
    const float* __restrict__ wu_w, const float* __restrict__ wu_b,
    const float* __restrict__ wv_w, const float* __restrict__ wv_b,
    __hip_bfloat16* __restrict__ w2bf, float* __restrict__ w2sum,
    float* __restrict__ b2) {
  __shared__ float red[8];
  const int tid = threadIdx.x;
  const int o = blockIdx.x;
  const bool isU = (o < 64);
  const float* wrow = isU ? (wu_w + o * D_MODEL) : (wv_w + (o - 64) * D_MODEL);
  const float scale = isU ? LOG2E : 1.0f;

  float s1 = 0.f, s2 = 0.f;
  #pragma unroll
  for (int cc = 0; cc < 2; ++cc) {
    const int c = tid + cc * 256;
    const float w  = wrow[c];
    const float w2 = w * ln_w[c] * scale;
    const __hip_bfloat16 hb = __float2bfloat16(w2);
    w2bf[o * D_MODEL + c] = hb;
    s1 += __bfloat162float(hb);
    s2 += w * ln_b[c];
  }
  #pragma unroll
  for (int off = 32; off; off >>= 1) {
    s1 += __shfl_xor(s1, off);
    s2 += __shfl_xor(s2, off);
  }
  const int wave = tid >> 6, lane = tid & 63;
  if (lane == 0) { red[wave] = s1; red[4 + wave] = s2; }
  __syncthreads();
  if (tid == 0) {
    w2sum[o] = red[0] + red[1] + red[2] + red[3];
    const float ss2 = red[4] + red[5] + red[6] + red[7];
    b2[o] = scale * ((isU ? wu_b[o] : wv_b[o - 64]) + ss2);
  }
}

// ---------------------------------------------------------------------------
// Kernel 1 (lnproj v2): grid = BN/16 blocks x 512 threads (8 waves).
// Phase 1: the 8 waves cooperatively build the 16x512 bf16 A-tile ONCE in
// LDS (wave w converts kc = 2w, 2w+1) + per-row LN partial stats.
// Phase 2: wave w = out-group w (outs w*16+ln16): 16 x {LDS A-frag read +
// global bf16 B-row load + MFMA}; LN applied in epilogue via folded w2sum/b2.
// vs r5: h_res traffic / 8, f32->bf16 convert VALU / 8, stats / 8.
// ---------------------------------------------------------------------------
__global__ __launch_bounds__(512) void lnproj_kernel(
    const float* __restrict__ h_res, const __hip_bfloat16* __restrict__ w2bf,
    const float* __restrict__ w2sum, const float* __restrict__ b2,
    float* __restrict__ U, __hip_bfloat16* __restrict__ Vbf, int N) {
  __shared__ short abuf[16 * 512];          // [kc][q][ln16][8], 16 KB
  __shared__ float sred[8][2][16];          // per-wave (sum,ssq) row partials
  const int tid = threadIdx.x;
  const int wv = tid >> 6, lane = tid & 63;
  const int q = lane >> 4, ln16 = lane & 15;
  const int row0 = blockIdx.x * 16;

  // ---- phase 1: build A tile + stats (wave wv owns kc = 2wv, 2wv+1) ----
  float sum = 0.f, ssq = 0.f;
  #pragma unroll
  for (int k2 = 0; k2 < 2; ++k2) {
    const int kc = wv * 2 + k2;
    const float* hp = h_res + (size_t)(row0 + ln16) * D_MODEL + kc * 32 + q * 8;
    const floatx4 x0 = *reinterpret_cast<const floatx4*>(hp);
    const floatx4 x1 = *reinterpret_cast<const floatx4*>(hp + 4);
    short8 a;
    #pragma unroll
    for (int e = 0; e < 4; ++e) {
      sum += x0[e]; ssq += x0[e] * x0[e];
      const __hip_bfloat16 hb = __float2bfloat16(x0[e]);
      a[e] = *reinterpret_cast<const short*>(&hb);
    }
    #pragma unroll
    for (int e = 0; e < 4; ++e) {
      sum += x1[e]; ssq += x1[e] * x1[e];
      const __hip_bfloat16 hb = __float2bfloat16(x1[e]);
      a[4 + e] = *reinterpret_cast<const short*>(&hb);
    }
    *reinterpret_cast<short8*>(&abuf[kc * 512 + q * 128 + ln16 * 8]) = a;
  }
  sum += __shfl_xor(sum, 16); sum += __shfl_xor(sum, 32);
  ssq += __shfl_xor(ssq, 16); ssq += __shfl_xor(ssq, 32);
  if (lane < 16) { sred[wv][0][ln16] = sum; sred[wv][1][ln16] = ssq; }
  __syncthreads();

  // ---- per-lane LN stats for the 4 C-rows this lane writes (q*4+r) ----
  float mu_r[4], rs_r[4];
  #pragma unroll
  for (int r = 0; r < 4; ++r) {
    const int row = q * 4 + r;
    float s = 0.f, s2 = 0.f;
    #pragma unroll
    for (int w = 0; w < 8; ++w) { s += sred[w][0][row]; s2 += sred[w][1][row]; }
    const float mu  = s * (1.0f / (float)D_MODEL);
    const float var = s2 * (1.0f / (float)D_MODEL) - mu * mu;
    mu_r[r] = mu;
    rs_r[r] = rsqrtf(var + 1e-5f);
  }

  // ---- phase 2: wave wv = out-group wv ----
  const int out = wv * 16 + ln16;            // 0..127
  const short* wp = reinterpret_cast<const short*>(w2bf);
  floatx4 acc = (floatx4){0.f, 0.f, 0.f, 0.f};
  #pragma unroll
  for (int kc = 0; kc < 16; ++kc) {
    const short8 afr = *reinterpret_cast<const short8*>(
        &abuf[kc * 512 + q * 128 + ln16 * 8]);
    const short8 bfr = *reinterpret_cast<const short8*>(
        wp + (size_t)out * D_MODEL + kc * 32 + q * 8);
    acc = __builtin_amdgcn_mfma_f32_16x16x32_bf16(afr, bfr, acc, 0, 0, 0);
  }

  const float ws = w2sum[out];
  const float bb = b2[out];
  #pragma unroll
  for (int r = 0; r < 4; ++r) {
    const int rowg = row0 + q * 4 + r;
    const float val = rs_r[r] * acc[r] - mu_r[r] * rs_r[r] * ws + bb;
    if (out < 64) {
      U[(size_t)rowg * D_LOW + out] = val;
    } else {
      Vbf[(size_t)rowg * D_LOW + (out - 64)] = __float2bfloat16(val);
    }
  }
}

// ---------------------------------------------------------------------------
// Kernel 2 (pair): grid (N, 2B) x 256. Each wave = 1 i x 96 j (6 tiles of 16).
// wfrag (the 6 MFMA A-fragments of row i) built COOPERATIVELY per block into
// LDS (384 slots / 256 threads) -> kills the wprep dispatch and the 9.4 MB
// wfragbuf round-trip; amortized over 4 waves x 6 tiles. All 6 V tiles
// issued up-front (12 loads in flight). Inline tbin. No ticket (r4 lesson:
// per-block fence+atomic serializes ~20 ns/block).  Assumes N % 128 == 0.
// ---------------------------------------------------------------------------
__global__ __launch_bounds__(256) void pair_kernel(
    const float* __restrict__ U, const __hip_bfloat16* __restrict__ Vbf,
    const float* __restrict__ wb_w, const float* __restrict__ wb_b,
    const float* __restrict__ x_true, const float* __restrict__ pmask,
    float* __restrict__ part, int N) {
  __shared__ short wsh[6 * 64 * 8];         // 6 KB A-fragments for row i
  __shared__ float rbuf[8];
  const int i    = blockIdx.x;
  const int b    = blockIdx.y >> 1;
  const int half = blockIdx.y & 1;
  const int tid  = threadIdx.x;
  const int wave = tid >> 6, lane = tid & 63;
  const int q = lane >> 4, ln16 = lane & 15;
  const int rowi = b * N + i;
  const int jbase = half * (N >> 1) + wave * (N >> 3);  // 96-j chunk per wave
  const int q4 = q * 4;

  // ---- V tiles up-front (longest latency first) ----
  const short* Vp = reinterpret_cast<const short*>(Vbf) + (size_t)b * N * D_LOW;
  short8 v[6][2];
  #pragma unroll
  for (int tl = 0; tl < 6; ++tl) {
    const size_t jr = jbase + tl * 16 + ln16;
    v[tl][0] = *reinterpret_cast<const short8*>(Vp + jr * D_LOW + q * 8);
    v[tl][1] = *reinterpret_cast<const short8*>(Vp + jr * D_LOW + 32 + q * 8);
  }

  // ---- cooperative wfrag build: slot = frag(0..5) x lane(0..63) ----
  // fr[e] = bf16(U[rowi][s*32+lq*8+e] * wb_w[n][s*32+lq*8+e]), n = t*16+l16
  // (identical rounding to the old wprep kernel)
  for (int slot = tid; slot < 384; slot += 256) {
    const int fidx = slot >> 6, l = slot & 63;
    const int t = fidx >> 1, s = fidx & 1;
    const int lq = l >> 4, l16 = l & 15;
    const int n = t * 16 + l16;
    short8 fr = (short8){0, 0, 0, 0, 0, 0, 0, 0};
    if (n < NBINS) {
      const float* up = U + (size_t)rowi * D_LOW + s * 32 + lq * 8;
      const float* wr = wb_w + (size_t)n * D_LOW + s * 32 + lq * 8;
      const floatx4 u0 = *reinterpret_cast<const floatx4*>(up);
      const floatx4 u1 = *reinterpret_cast<const floatx4*>(up + 4);
      const floatx4 w0 = *reinterpret_cast<const floatx4*>(wr);
      const floatx4 w1 = *reinterpret_cast<const floatx4*>(wr + 4);
      #pragma unroll
      for (int e = 0; e < 4; ++e) {
        const __hip_bfloat16 h0 = __float2bfloat16(u0[e] * w0[e]);
        const __hip_bfloat16 h1 = __float2bfloat16(u1[e] * w1[e]);
        fr[e]     = *reinterpret_cast<const short*>(&h0);
        fr[4 + e] = *reinterpret_cast<const short*>(&h1);
      }
    }
    *reinterpret_cast<short8*>(&wsh[slot * 8]) = fr;
  }

  // ---- tbin: 6 tiles ----
  const float xi0 = x_true[rowi * 3 + 0];
  const float xi1 = x_true[rowi * 3 + 1];
  const float xi2 = x_true[rowi * 3 + 2];
  const float pmi = pmask[rowi];
  const float BW  = (22.0f - 2.0f) / 38.0f;
  int tbv[6];
  #pragma unroll
  for (int tl = 0; tl < 6; ++tl) {
    const int rowj = b * N + jbase + tl * 16 + ln16;
    const float dx = xi0 - x_true[rowj * 3 + 0];
    const float dy = xi1 - x_true[rowj * 3 + 1];
    const float dz = xi2 - x_true[rowj * 3 + 2];
    const float d  = sqrtf(dx * dx + dy * dy + dz * dz);
    int tb = (int)((d - 2.0f) / BW);
    tb = tb < 0 ? 0 : (tb > NBINS - 1 ? NBINS - 1 : tb);
    tbv[tl] = (pmi * pmask[rowj] > 0.f) ? tb : -1;
  }

  floatx4 bias_init[3];
  #pragma unroll
  for (int t = 0; t < 3; ++t)
    #pragma unroll
    for (int r = 0; r < 4; ++r) {
      const int bin = t * 16 + q * 4 + r;
      bias_init[t][r] = (bin < NBINS) ? LOG2E * wb_b[bin] : -INFINITY;
    }

  __syncthreads();
  short8 wfrag[3][2];
  #pragma unroll
  for (int t = 0; t < 3; ++t)
    #pragma unroll
    for (int s = 0; s < 2; ++s)
      wfrag[t][s] = *reinterpret_cast<const short8*>(
          &wsh[((t * 2 + s) * 64 + lane) * 8]);

  float ce_sum = 0.f, cnt_sum = 0.f;
  #pragma unroll
  for (int tl = 0; tl < 6; ++tl) {
    floatx4 f[3];
    #pragma unroll
    for (int t = 0; t < 3; ++t) {
      floatx4 a = bias_init[t];
      a = __builtin_amdgcn_mfma_f32_16x16x32_bf16(wfrag[t][0], v[tl][0], a, 0, 0, 0);
      a = __builtin_amdgcn_mfma_f32_16x16x32_bf16(wfrag[t][1], v[tl][1], a, 0, 0, 0);
      f[t] = a;
    }

    const int tb  = tbv[tl];
    const int tbq = tb - q4;
    float s0 = 0.f, s1 = 0.f, s2 = 0.f, s3 = 0.f, lt = 0.f;
    #pragma unroll
    for (int t = 0; t < 3; ++t) {
      const floatx4 fv = f[t];
      s0 += __builtin_amdgcn_exp2f(fv[0]);
      s1 += __builtin_amdgcn_exp2f(fv[1]);
      s2 += __builtin_amdgcn_exp2f(fv[2]);
      s3 += __builtin_amdgcn_exp2f(fv[3]);
      lt += (tbq == t * 16 + 0) ? fv[0] : 0.f;
      lt += (tbq == t * 16 + 1) ? fv[1] : 0.f;
      lt += (tbq == t * 16 + 2) ? fv[2] : 0.f;
      lt += (tbq == t * 16 + 3) ? fv[3] : 0.f;
    }
    float ssum = (s0 + s1) + (s2 + s3);
    ssum += __shfl_xor(ssum, 16); ssum += __shfl_xor(ssum, 32);
    const float ok = (tb >= 0) ? 1.f : 0.f;
    ce_sum  += ok * LN2 * (__builtin_amdgcn_logf(ssum) - 4.0f * lt);
    cnt_sum += ok;
  }

  #pragma unroll
  for (int off = 32; off; off >>= 1) {
    ce_sum  += __shfl_xor(ce_sum, off);
    cnt_sum += __shfl_xor(cnt_sum, off);
  }
  if (lane == 0) { rbuf[wave] = ce_sum; rbuf[4 + wave] = cnt_sum; }
  __syncthreads();
  if (tid == 0) {
    const size_t slot = ((size_t)blockIdx.y * N + blockIdx.x) * 2;
    part[slot + 0] = rbuf[0] + rbuf[1] + rbuf[2] + rbuf[3];
    part[slot + 1] = rbuf[4] + rbuf[5] + rbuf[6] + rbuf[7];
  }
}

// ---------------------------------------------------------------------------
// Kernel 3: finalize — batch b owns slots [b*2N, (b+1)*2N) (2 halves x N).
// ---------------------------------------------------------------------------
__global__ __launch_bounds__(256) void finalize_kernel(
    const float* __restrict__ part, float* __restrict__ out, int N, int B) {
  __shared__ float red[8];
  const int tid = threadIdx.x, wave = tid >> 6, lane = tid & 63;
  float loss = 0.f, vcount = 0.f;
  const int nper = 2 * N;
  for (int b = 0; b < B; ++b) {
    float ce = 0.f, cnt = 0.f;
    for (int e = tid; e < nper; e += 256) {
      const size_t base = ((size_t)b * nper + e) * 2;
      ce  += part[base + 0];
      cnt += part[base + 1];
    }
    #pragma unroll
    for (int off = 32; off; off >>= 1) {
      ce  += __shfl_xor(ce, off);
      cnt += __shfl_xor(cnt, off);
    }
    if (lane == 0) { red[wave] = ce; red[4 + wave] = cnt; }
    __syncthreads();
    if (tid == 0) {
      const float s = red[0] + red[1] + red[2] + red[3];
      const float c = red[4] + red[5] + red[6] + red[7];
      if (c > 0.f) { loss += s / fmaxf(c, 1.f); vcount += 1.f; }
    }
    __syncthreads();
  }
  if (tid == 0) out[0] = (vcount > 0.f) ? loss / vcount : 0.f;
}

extern "C" void kernel_launch(void* const* d_in, const int* in_sizes, int n_in,
                              void* d_out, int out_size, void* d_ws, size_t ws_size,
                              hipStream_t stream) {
  const float* h_res  = (const float*)d_in[0];
  const float* x_true = (const float*)d_in[1];
  const float* pmask  = (const float*)d_in[2];
  const float* ln_w   = (const float*)d_in[3];
  const float* ln_b   = (const float*)d_in[4];
  const float* wu_w   = (const float*)d_in[5];
  const float* wu_b   = (const float*)d_in[6];
  const float* wv_w   = (const float*)d_in[7];
  const float* wv_b   = (const float*)d_in[8];
  const float* wb_w   = (const float*)d_in[9];
  const float* wb_b   = (const float*)d_in[10];

  const int B  = 2;
  const int N  = in_sizes[2] / B;
  const int BN = B * N;

  // ws: U f32[BN*64] | Vbf bf16[BN*64] | part f32[2B*N*2]
  //     | w2bf bf16[128*512] | w2sum f32[128] | b2 f32[128]
  float* U = (float*)d_ws;
  __hip_bfloat16* Vbf = (__hip_bfloat16*)(U + (size_t)BN * D_LOW);
  float* part = (float*)(Vbf + (size_t)BN * D_LOW);
  __hip_bfloat16* w2bf = (__hip_bfloat16*)(part + (size_t)2 * B * N * 2);
  float* w2sum = (float*)(w2bf + 128 * D_MODEL);
  float* b2    = w2sum + 128;

  prep_kernel<<<128, 256, 0, stream>>>(ln_w, ln_b, wu_w, wu_b, wv_w, wv_b,
                                       w2bf, w2sum, b2);
  lnproj_kernel<<<BN / 16, 512, 0, stream>>>(h_res, w2bf, w2sum, b2,
                                             U, Vbf, N);
  pair_kernel<<<dim3(N, 2 * B), 256, 0, stream>>>(
      U, Vbf, wb_w, wb_b, x_true, pmask, part, N);
  finalize_kernel<<<1, 256, 0, stream>>>(part, (float*)d_out, N, B);
}